// Round 1
// baseline (395.681 us; speedup 1.0000x reference)
//
#include <hip/hip_runtime.h>

#define NKK 8192
#define NQQ 8192
#define DDIM 64

typedef __attribute__((ext_vector_type(8))) short short8;
typedef __attribute__((ext_vector_type(4))) float f32x4;

static __device__ __forceinline__ unsigned short f2b(float x) {
  unsigned int u = __builtin_bit_cast(unsigned int, x);
  unsigned int r = (u + 0x7fffu + ((u >> 16) & 1u)) >> 16;  // RTNE
  return (unsigned short)r;
}

// ---------------- pre-convert: Q,K -> bf16 row-major ; V -> bf16 transposed [64][8192]
__global__ __launch_bounds__(256) void prep_kernel(
    const float* __restrict__ K, const float* __restrict__ V, const float* __restrict__ Q,
    unsigned short* __restrict__ Kb, unsigned short* __restrict__ Qb, unsigned short* __restrict__ Vtb) {
  __shared__ unsigned short vt[64][72];
  const int b = blockIdx.x, t = threadIdx.x;
  const size_t base = (size_t)b * 4096;
#pragma unroll
  for (int i = 0; i < 4; ++i) {
    size_t idx = base + (size_t)i * 1024 + (size_t)t * 4;
    float4 kv = *(const float4*)(K + idx);
    float4 qv = *(const float4*)(Q + idx);
    ushort4 ko, qo;
    ko.x = f2b(kv.x); ko.y = f2b(kv.y); ko.z = f2b(kv.z); ko.w = f2b(kv.w);
    qo.x = f2b(qv.x); qo.y = f2b(qv.y); qo.z = f2b(qv.z); qo.w = f2b(qv.w);
    *(ushort4*)(Kb + idx) = ko;
    *(ushort4*)(Qb + idx) = qo;
  }
  const int r0 = b * 64;
#pragma unroll
  for (int i = 0; i < 4; ++i) {
    int kl = (t >> 4) + i * 16;
    int c4 = (t & 15) * 4;
    float4 v = *(const float4*)(V + (size_t)(r0 + kl) * 64 + c4);
    vt[c4 + 0][kl] = f2b(v.x);
    vt[c4 + 1][kl] = f2b(v.y);
    vt[c4 + 2][kl] = f2b(v.z);
    vt[c4 + 3][kl] = f2b(v.w);
  }
  __syncthreads();
  {
    int d = t >> 2, kc = (t & 3) * 16;
    uint4 a0 = *(const uint4*)(&vt[d][kc]);
    uint4 a1 = *(const uint4*)(&vt[d][kc + 8]);
    *(uint4*)(Vtb + (size_t)d * NKK + r0 + kc) = a0;
    *(uint4*)(Vtb + (size_t)d * NKK + r0 + kc + 8) = a1;
  }
}

// ---------------- main fused attention
__global__ __launch_bounds__(512, 2) void attn_kernel(
    const float* __restrict__ mg, const unsigned short* __restrict__ Kb,
    const unsigned short* __restrict__ Qb, const unsigned short* __restrict__ Vtb,
    float* __restrict__ out) {
  __shared__ unsigned short Pl[8][32 * 40];       // per-wave P tile, row stride 40 bf16 (80B)
  __shared__ float accslot[4][8][4][64];          // 32 KB combine slots
  __shared__ float lslot[4][8][4];

  const int tid = threadIdx.x;
  const int wid = tid >> 6;
  const int lane = tid & 63;
  const int c = lane & 15;      // col-within-16
  const int g = lane >> 4;      // lane group 0..3
  const int q0 = blockIdx.x * 32;

  const float LOG2E = 1.4426950408889634f;
  const float C1 = 0.125f * LOG2E;        // scale = 1/sqrt(64)
  const float MM = -8.0f * LOG2E;         // static max shift M0 = 8

  // Q fragments (A operand): qf[qs*2+dh], lane holds Q[q0+qs*16+c][dh*32+8g .. +7]
  short8 qf[4];
#pragma unroll
  for (int qs = 0; qs < 2; ++qs)
#pragma unroll
    for (int dh = 0; dh < 2; ++dh)
      qf[qs * 2 + dh] = __builtin_bit_cast(
          short8, *(const uint4*)(Qb + (size_t)(q0 + qs * 16 + c) * 64 + dh * 32 + 8 * g));

  f32x4 acc[2][4];
#pragma unroll
  for (int a = 0; a < 2; ++a)
#pragma unroll
    for (int b2 = 0; b2 < 4; ++b2) acc[a][b2] = f32x4{0.f, 0.f, 0.f, 0.f};
  float lsum[8];
#pragma unroll
  for (int n = 0; n < 8; ++n) lsum[n] = 0.f;

  unsigned short* Pw = &Pl[wid][0];
  const unsigned short* Pr = &Pl[wid][c * 40 + 8 * g];
  const unsigned int mbase = (unsigned int)(q0 + 4 * g) * (unsigned int)NKK + (unsigned int)c;

  float mA[16], mB[16];
  short8 kA[4], kB[4], vA[4], vB[4];

  auto loadM = [&](int t, float (&mb)[16]) {
    const unsigned int toff = (unsigned int)((wid + 8 * t) * 32);
    const float* mp = mg + mbase + toff;
#pragma unroll
    for (int qs = 0; qs < 2; ++qs)
#pragma unroll
      for (int ks = 0; ks < 2; ++ks)
#pragma unroll
        for (int i = 0; i < 4; ++i)
          mb[qs * 8 + ks * 4 + i] = mp[(unsigned int)(qs * 16 + i) * NKK + ks * 16];
  };

  auto loadKV = [&](int t, short8 (&kf)[4], short8 (&vf)[4]) {
    const int k0 = (wid + 8 * t) * 32;
#pragma unroll
    for (int ks = 0; ks < 2; ++ks)
#pragma unroll
      for (int dh = 0; dh < 2; ++dh)
        kf[ks * 2 + dh] = __builtin_bit_cast(
            short8, *(const uint4*)(Kb + (size_t)(k0 + ks * 16 + c) * 64 + dh * 32 + 8 * g));
#pragma unroll
    for (int dt = 0; dt < 4; ++dt)
      vf[dt] = __builtin_bit_cast(
          short8, *(const uint4*)(Vtb + (size_t)(dt * 16 + c) * NKK + k0 + 8 * g));
  };

  auto compute = [&](const float (&mb)[16], const short8 (&kf)[4], const short8 (&vf)[4]) {
    f32x4 s[2][2];
#pragma unroll
    for (int qs = 0; qs < 2; ++qs)
#pragma unroll
      for (int ks = 0; ks < 2; ++ks) {
        f32x4 z = f32x4{0.f, 0.f, 0.f, 0.f};
        z = __builtin_amdgcn_mfma_f32_16x16x32_bf16(qf[qs * 2 + 0], kf[ks * 2 + 0], z, 0, 0, 0);
        z = __builtin_amdgcn_mfma_f32_16x16x32_bf16(qf[qs * 2 + 1], kf[ks * 2 + 1], z, 0, 0, 0);
        s[qs][ks] = z;
      }
#pragma unroll
    for (int qs = 0; qs < 2; ++qs)
#pragma unroll
      for (int ks = 0; ks < 2; ++ks)
#pragma unroll
        for (int i = 0; i < 4; ++i) {
          float e = __builtin_fmaf(s[qs][ks][i], C1,
                                   __builtin_fmaf(mb[qs * 8 + ks * 4 + i], LOG2E, MM));
          float p = __builtin_amdgcn_exp2f(e);
          lsum[qs * 4 + i] += p;
          Pw[(qs * 16 + 4 * g + i) * 40 + ks * 16 + c] = f2b(p);
        }
    short8 pa[2];
#pragma unroll
    for (int qs = 0; qs < 2; ++qs)
      pa[qs] = __builtin_bit_cast(short8, *(const uint4*)(Pr + qs * 640));
#pragma unroll
    for (int qs = 0; qs < 2; ++qs)
#pragma unroll
      for (int dt = 0; dt < 4; ++dt)
        acc[qs][dt] = __builtin_amdgcn_mfma_f32_16x16x32_bf16(pa[qs], vf[dt], acc[qs][dt], 0, 0, 0);
  };

  // software-pipelined main loop: 32 tiles of 32 keys, 1-deep register double buffer
  loadM(0, mA);
  loadKV(0, kA, vA);
  for (int t = 0; t < 32; t += 2) {
    loadM(t + 1, mB);
    loadKV(t + 1, kB, vB);
    compute(mA, kA, vA);
    if (t + 2 < 32) {
      loadM(t + 2, mA);
      loadKV(t + 2, kA, vA);
    }
    compute(mB, kB, vB);
  }

  // finish row sums: butterfly over the 16-lane group (k lives in lane bits 0..3 + in-lane)
#pragma unroll
  for (int n = 0; n < 8; ++n) {
    float v = lsum[n];
    v += __shfl_xor(v, 1);
    v += __shfl_xor(v, 2);
    v += __shfl_xor(v, 4);
    v += __shfl_xor(v, 8);
    lsum[n] = v;
  }

  auto writeSlot = [&](int slot) {
#pragma unroll
    for (int qs = 0; qs < 2; ++qs)
#pragma unroll
      for (int dt = 0; dt < 4; ++dt)
#pragma unroll
        for (int i = 0; i < 4; ++i) accslot[slot][qs * 4 + dt][i][lane] = acc[qs][dt][i];
    if (c == 0) {
#pragma unroll
      for (int n = 0; n < 8; ++n) lslot[slot][n][g] = lsum[n];
    }
  };
  auto addSlot = [&](int slot) {
#pragma unroll
    for (int qs = 0; qs < 2; ++qs)
#pragma unroll
      for (int dt = 0; dt < 4; ++dt)
#pragma unroll
        for (int i = 0; i < 4; ++i) acc[qs][dt][i] += accslot[slot][qs * 4 + dt][i][lane];
#pragma unroll
    for (int n = 0; n < 8; ++n) lsum[n] += lslot[slot][n][g];
  };

  // 8 -> 4 -> 2 -> 1 tree combine of k-split partials (plain sums: no max-merge needed)
  if (wid >= 4) writeSlot(wid - 4);
  __syncthreads();
  if (wid < 4) addSlot(wid);
  __syncthreads();
  if (wid == 2 || wid == 3) writeSlot(wid - 2);
  __syncthreads();
  if (wid < 2) addSlot(wid);
  __syncthreads();
  if (wid == 1) writeSlot(0);
  __syncthreads();
  if (wid == 0) {
    addSlot(0);
#pragma unroll
    for (int qs = 0; qs < 2; ++qs)
#pragma unroll
      for (int i = 0; i < 4; ++i) {
        float rl = 1.0f / lsum[qs * 4 + i];
        int q = q0 + qs * 16 + 4 * g + i;
#pragma unroll
        for (int dt = 0; dt < 4; ++dt)
          out[(size_t)q * 64 + dt * 16 + c] = acc[qs][dt][i] * rl;
      }
  }
}

extern "C" void kernel_launch(void* const* d_in, const int* in_sizes, int n_in,
                              void* d_out, int out_size, void* d_ws, size_t ws_size,
                              hipStream_t stream) {
  (void)in_sizes; (void)n_in; (void)out_size; (void)ws_size;
  const float* K = (const float*)d_in[0];
  const float* V = (const float*)d_in[1];
  const float* Q = (const float*)d_in[2];
  const float* mg = (const float*)d_in[3];
  float* out = (float*)d_out;

  unsigned short* Kb = (unsigned short*)d_ws;
  unsigned short* Qb = Kb + (size_t)NKK * DDIM;
  unsigned short* Vtb = Qb + (size_t)NQQ * DDIM;

  prep_kernel<<<128, 256, 0, stream>>>(K, V, Q, Kb, Qb, Vtb);
  attn_kernel<<<256, 512, 0, stream>>>(mg, Kb, Qb, Vtb, out);
}